// Round 6
// baseline (45478.998 us; speedup 1.0000x reference)
//
#include <hip/hip_runtime.h>
#include <stdint.h>
#include <stddef.h>

typedef _Float16 h2 __attribute__((ext_vector_type(2)));
typedef uint32_t u32x16 __attribute__((ext_vector_type(16)));

#define T_STEPS 32768
#define HDIM    256

__device__ __forceinline__ float sigmoidf_(float x) {
    return 1.0f / (1.0f + __expf(-x));
}
__device__ __forceinline__ float tanhf_(float x) {
    float e2 = __expf(2.0f * x);
    return 1.0f - 2.0f / (e2 + 1.0f);
}
__device__ __forceinline__ h2 bc_(uint32_t u) { return __builtin_bit_cast(h2, u); }
__device__ __forceinline__ uint32_t cvt_pair(float2 v) {
    h2 q; q.x = (_Float16)v.x; q.y = (_Float16)v.y;
    return __builtin_bit_cast(uint32_t, q);
}

// Load 16 f32 pairs -> f16 pairs into an ext_vector at LITERAL indices
// (insertelement, no alloca — R1..R5 used arrays, which stayed in scratch
// and made every weight access a scratch load: the 800+ MB FETCH signature).
#define LD16(dst, p, B) \
    dst[0]  = cvt_pair((p)[(B) + 0]);  dst[1]  = cvt_pair((p)[(B) + 1]);  \
    dst[2]  = cvt_pair((p)[(B) + 2]);  dst[3]  = cvt_pair((p)[(B) + 3]);  \
    dst[4]  = cvt_pair((p)[(B) + 4]);  dst[5]  = cvt_pair((p)[(B) + 5]);  \
    dst[6]  = cvt_pair((p)[(B) + 6]);  dst[7]  = cvt_pair((p)[(B) + 7]);  \
    dst[8]  = cvt_pair((p)[(B) + 8]);  dst[9]  = cvt_pair((p)[(B) + 9]);  \
    dst[10] = cvt_pair((p)[(B) + 10]); dst[11] = cvt_pair((p)[(B) + 11]); \
    dst[12] = cvt_pair((p)[(B) + 12]); dst[13] = cvt_pair((p)[(B) + 13]); \
    dst[14] = cvt_pair((p)[(B) + 14]); dst[15] = cvt_pair((p)[(B) + 15]);

#define FD(wv, ph, acc) acc = __builtin_amdgcn_fdot2(bc_(wv), ph, acc, false)

// Consume one uint4 (4 h-pairs) against pairs J..J+3 of the three gate vectors
#define DOT4(WV, ZV, NV, J, Q) {                                   \
    h2 p0 = bc_((Q).x), p1 = bc_((Q).y), p2 = bc_((Q).z), p3 = bc_((Q).w); \
    FD(WV[(J) + 0], p0, ar); FD(ZV[(J) + 0], p0, az); FD(NV[(J) + 0], p0, an); \
    FD(WV[(J) + 1], p1, ar); FD(ZV[(J) + 1], p1, az); FD(NV[(J) + 1], p1, an); \
    FD(WV[(J) + 2], p2, ar); FD(ZV[(J) + 2], p2, az); FD(NV[(J) + 2], p2, an); \
    FD(WV[(J) + 3], p3, ar); FD(ZV[(J) + 3], p3, az); FD(NV[(J) + 3], p3, an); }

// One block, 512 threads = 8 waves = 2 waves/SIMD -> 256-VGPR budget via
// __launch_bounds__(512,1) (hipcc: waves-per-eu = 8*1/4 = 2).
// Thread (wave w, lane l): column-half hq = l>>5, result-row ri = w*32+(l&31).
// Owns GRU rows {ri, 256+ri, 512+ri}, columns [hq*128, hq*128+128):
// 3 gates x 4 ext-vectors x 16 f16-pairs = 192 VGPRs of weights, all SSA.
// Halves combined with one shfl_down(32) per gate. h is f16 in
// double-buffered LDS (broadcast reads); x staged in LDS (128 KB).
__global__ __launch_bounds__(512, 1)
void aether_gru_kernel(const float* __restrict__ xg,
                       const float* __restrict__ wih,
                       const float* __restrict__ whh,
                       const float* __restrict__ bih,
                       const float* __restrict__ bhh,
                       const float* __restrict__ wfc,
                       const float* __restrict__ bfc,
                       float* __restrict__ out) {
    const int tid  = threadIdx.x;
    const int lane = tid & 63;
    const int w    = tid >> 6;              // wave 0..7
    const int hq   = lane >> 5;             // column half 0/1
    const int ri   = w * 32 + (lane & 31);  // result row 0..255

    __shared__ float xlds[T_STEPS + 2];
    __shared__ __align__(16) _Float16 hbuf[2][HDIM];
    __shared__ float pp[2][8];

    // ---- stage x into LDS (coalesced float4) ----
    {
        const float4* xs4 = (const float4*)xg;
        float4* xd4 = (float4*)xlds;
        #pragma unroll
        for (int j = 0; j < T_STEPS / 4 / 512; ++j)
            xd4[tid + 512 * j] = xs4[tid + 512 * j];
        if (tid == 0) { xlds[T_STEPS] = 0.0f; xlds[T_STEPS + 1] = 0.0f; }
    }

    // ---- weights: 3 gates x 64 f16-pairs as SSA ext-vectors ----
    u32x16 wr0, wr1, wr2, wr3, wz0, wz1, wz2, wz3, wn0, wn1, wn2, wn3;
    {
        const float2* p = (const float2*)(whh + (size_t)ri * HDIM) + hq * 64;
        LD16(wr0, p, 0) LD16(wr1, p, 16) LD16(wr2, p, 32) LD16(wr3, p, 48)
    }
    {
        const float2* p = (const float2*)(whh + (size_t)(HDIM + ri) * HDIM) + hq * 64;
        LD16(wz0, p, 0) LD16(wz1, p, 16) LD16(wz2, p, 32) LD16(wz3, p, 48)
    }
    {
        const float2* p = (const float2*)(whh + (size_t)(2 * HDIM + ri) * HDIM) + hq * 64;
        LD16(wn0, p, 0) LD16(wn1, p, 16) LD16(wn2, p, 32) LD16(wn3, p, 48)
    }

    // per-result-row scalar constants
    const float wxr = wih[2 * ri],              wdr = wih[2 * ri + 1];
    const float wxz = wih[2 * (HDIM + ri)],     wdz = wih[2 * (HDIM + ri) + 1];
    const float wxn = wih[2 * (2 * HDIM + ri)], wdn = wih[2 * (2 * HDIM + ri) + 1];
    const float br = bih[ri], bz = bih[HDIM + ri], bn = bih[2 * HDIM + ri];
    // b_hh folded into the accumulator of column-half 0 only
    const float cr = (hq == 0) ? bhh[ri] : 0.0f;
    const float cz = (hq == 0) ? bhh[HDIM + ri] : 0.0f;
    const float cn = (hq == 0) ? bhh[2 * HDIM + ri] : 0.0f;
    const float wf = wfc[ri];
    const float bf = bfc[0];

    if (tid < HDIM) hbuf[0][tid] = (_Float16)0.0f;
    __syncthreads();

    // ---- sequential state (uniform across threads -> uniform branches) ----
    float hprev    = 0.0f;
    float last_val = xlds[0] + 1.24f;       // xs[0] + (2*THRESHOLD + 1.0)
    float last_t   = 0.0f;
    int   cnt      = 0;
    int   cur      = 0;                     // hbuf read index
    int   pe       = 0;                     // pp parity
    float cur_pred = 0.0f;

    float xc = xlds[0];
    float xn = xlds[1];

    float* recon = out;
    float* idxp  = out + T_STEPS + 1;

    for (int t = 0; t < T_STEPS; ++t) {
        float xf = xlds[t + 2];                      // LDS prefetch, 2 ahead
        const float tf = (float)t;
        const bool ev = fabsf(xc - last_val) >= 0.12f;

        if (ev) {
            const float dtv = (tf - last_t) * 0.01f;
            const float gir = fmaf(wxr, xc, fmaf(wdr, dtv, br));
            const float giz = fmaf(wxz, xc, fmaf(wdz, dtv, bz));
            const float gin = fmaf(wxn, xc, fmaf(wdn, dtv, bn));

            float ar = cr, az = cz, an = cn;
            const uint4* hb = (const uint4*)(&hbuf[cur][hq * 128]);
            {
                uint4 q0 = hb[0], q1 = hb[1], q2 = hb[2], q3 = hb[3];
                DOT4(wr0, wz0, wn0, 0,  q0)
                DOT4(wr0, wz0, wn0, 4,  q1)
                DOT4(wr0, wz0, wn0, 8,  q2)
                DOT4(wr0, wz0, wn0, 12, q3)
                q0 = hb[4]; q1 = hb[5]; q2 = hb[6]; q3 = hb[7];
                DOT4(wr1, wz1, wn1, 0,  q0)
                DOT4(wr1, wz1, wn1, 4,  q1)
                DOT4(wr1, wz1, wn1, 8,  q2)
                DOT4(wr1, wz1, wn1, 12, q3)
                q0 = hb[8]; q1 = hb[9]; q2 = hb[10]; q3 = hb[11];
                DOT4(wr2, wz2, wn2, 0,  q0)
                DOT4(wr2, wz2, wn2, 4,  q1)
                DOT4(wr2, wz2, wn2, 8,  q2)
                DOT4(wr2, wz2, wn2, 12, q3)
                q0 = hb[12]; q1 = hb[13]; q2 = hb[14]; q3 = hb[15];
                DOT4(wr3, wz3, wn3, 0,  q0)
                DOT4(wr3, wz3, wn3, 4,  q1)
                DOT4(wr3, wz3, wn3, 8,  q2)
                DOT4(wr3, wz3, wn3, 12, q3)
            }
            // combine column-halves: low 32 lanes get full sums
            ar += __shfl_down(ar, 32);
            az += __shfl_down(az, 32);
            an += __shfl_down(an, 32);

            const float r = sigmoidf_(gir + ar);
            const float z = sigmoidf_(giz + az);
            const float n = tanhf_(fmaf(r, an, gin));
            const float hnew = fmaf(z, hprev, (1.0f - z) * n);
            hprev = hnew;                            // valid on low-half lanes

            if ((lane >> 5) == 0) hbuf[cur ^ 1][ri] = (_Float16)hnew;

            // fc partial: zero upper half, reduce 32 -> lane 0
            float pv = (lane < 32) ? hnew * wf : 0.0f;
            pv += __shfl_down(pv, 16);
            pv += __shfl_down(pv, 8);
            pv += __shfl_down(pv, 4);
            pv += __shfl_down(pv, 2);
            pv += __shfl_down(pv, 1);
            if (lane == 0) pp[pe][w] = pv;
            if (tid == 0) idxp[cnt] = tf;            // ascending -> sorted

            last_val = xc;
            last_t   = tf;
            cnt++;

            __syncthreads();                          // publish hbuf + pp
            cur ^= 1;
            if (tid == 0) {
                const float* q = &pp[pe][0];
                cur_pred = ((q[0] + q[1]) + (q[2] + q[3]))
                         + ((q[4] + q[5]) + (q[6] + q[7])) + bf;
            }
            pe ^= 1;
        }

        if (tid == 0) recon[t] = cur_pred;            // piecewise-constant pred
        xc = xn; xn = xf;
    }

    if (tid == 0) out[T_STEPS] = (float)cnt;          // n_events
    for (int j = cnt + tid; j < T_STEPS; j += 512)
        idxp[j] = 32768.0f;                           // pad with T
}

extern "C" void kernel_launch(void* const* d_in, const int* in_sizes, int n_in,
                              void* d_out, int out_size, void* d_ws, size_t ws_size,
                              hipStream_t stream) {
    const float* x    = (const float*)d_in[0];
    const float* wih  = (const float*)d_in[1];
    const float* whh  = (const float*)d_in[2];
    const float* bih  = (const float*)d_in[3];
    const float* bhh  = (const float*)d_in[4];
    const float* wfc  = (const float*)d_in[5];
    const float* bfc  = (const float*)d_in[6];
    float* out = (float*)d_out;

    hipLaunchKernelGGL(aether_gru_kernel, dim3(1), dim3(512), 0, stream,
                       x, wih, whh, bih, bhh, wfc, bfc, out);
}